// Round 8
// baseline (107.079 us; speedup 1.0000x reference)
//
#include <hip/hip_runtime.h>
#include <math.h>

#define IMH 512
#define IMW 512
#define RB    16    // output rows per wave-band
#define NBAND 32    // IMH / RB
#define NWC   10    // wave-columns: out width 56 each, c0 = 56*wc - 4
#define OUTW  56
#define REPEATS 2   // INSTRUMENTATION: run each band twice so the dispatch
                    // exceeds the top-5 cutoff and cold-vs-warm shows in dur.

__device__ __forceinline__ int reflect_i(int v, int n) {
    if (v < 0) v = -v;
    if (v >= n) v = 2 * n - 2 - v;
    return v;
}
__device__ __forceinline__ float dpp_shr1(float x) {   // lane i <- lane i-1
    int i = __float_as_int(x);
    return __int_as_float(__builtin_amdgcn_update_dpp(i, i, 0x138, 0xF, 0xF, false));
}
__device__ __forceinline__ float dpp_shl1(float x) {   // lane i <- lane i+1
    int i = __float_as_int(x);
    return __int_as_float(__builtin_amdgcn_update_dpp(i, i, 0x130, 0xF, 0xF, false));
}

template <bool YB>
__device__ __forceinline__ void run_band(const float* __restrict__ p0,
                                         const float* __restrict__ p1,
                                         const float* __restrict__ p2,
                                         float* __restrict__ outp,
                                         int y0, int rx, int cx,
                                         int ixm, int ixp, int lane) {
    const float w0 = 0.05448868f, w1 = 0.24420134f, w2 = 0.40261995f;

    float h0 = 0, h1 = 0, h2 = 0, h3 = 0;
    float b_1 = 0, b_0 = 0, bl_1 = 0, bl_0 = 0, br_1 = 0, br_0 = 0;
    float m_1 = 0, m_0 = 0, ml_1 = 0, ml_0 = 0, mr_1 = 0, mr_0 = 0;
    float gxp = 0, gyp = 0;

    auto process = [&](int yL, float gray) {
        float gm1 = dpp_shr1(gray);
        float gm2 = dpp_shr1(gm1);
        float gp1 = dpp_shl1(gray);
        float gp2 = dpp_shl1(gp1);
        float hnew = w0 * (gm2 + gp2) + w1 * (gm1 + gp1) + w2 * gray;
        float bnew = w0 * (h0 + hnew) + w1 * (h1 + h3) + w2 * h2;
        float blnew = __shfl(bnew, ixm);
        float brnew = __shfl(bnew, ixp);
        int u = yL - 3;
        float ta  = (YB && u == 0) ? b_0 : b_1;
        float tla = (YB && u == 0) ? bl_0 : bl_1;
        float tra = (YB && u == 0) ? br_0 : br_1;
        float tb  = (YB && u == IMH - 1) ? b_0 : bnew;
        float tlb = (YB && u == IMH - 1) ? bl_0 : blnew;
        float trb = (YB && u == IMH - 1) ? br_0 : brnew;
        float gx = (tra - tla) + 2.0f * (br_0 - bl_0) + (trb - tlb);
        float gy = (tlb - tla) + 2.0f * (tb - ta) + (trb - tra);
        float mnew = sqrtf(gx * gx + gy * gy + 1e-6f);
        if ((unsigned)cx >= (unsigned)IMW) mnew = 0.0f;
        float mlnew = dpp_shr1(mnew);
        float mrnew = dpp_shl1(mnew);
        int s = yL - 4;
        if (s >= y0) {
            float pm  = (YB && s == 0) ? 0.0f : m_1;
            float pml = (YB && s == 0) ? 0.0f : ml_1;
            float pmr = (YB && s == 0) ? 0.0f : mr_1;
            float nm  = (YB && s == IMH - 1) ? 0.0f : mnew;
            float nml = (YB && s == IMH - 1) ? 0.0f : mlnew;
            float nmr = (YB && s == IMH - 1) ? 0.0f : mrnew;
            float ax = fabsf(gxp), ay = fabsf(gyp);
            bool ew = (ay <= 0.41421356237f * ax);
            bool ns = (ay >= 2.41421356237f * ax);
            bool d1 = (gxp * gyp > 0.0f);
            float n1 = ew ? mr_0 : (ns ? nm : (d1 ? pmr : nmr));
            float n2 = ew ? ml_0 : (ns ? pm : (d1 ? nml : pml));
            float mag = m_0;
            float o = (mag > n1 && mag > n2) ? mag : 0.0f;
            if (lane >= 4 && lane < 60 && (unsigned)cx < (unsigned)IMW)
                __builtin_nontemporal_store(o, &outp[(size_t)s * IMW + cx]);
        }
        h0 = h1; h1 = h2; h2 = h3; h3 = hnew;
        b_1 = b_0;  b_0 = bnew;
        bl_1 = bl_0; bl_0 = blnew;
        br_1 = br_0; br_0 = brnew;
        m_1 = m_0;  m_0 = mnew;
        ml_1 = ml_0; ml_0 = mlnew;
        mr_1 = mr_0; mr_0 = mrnew;
        gxp = gx; gyp = gy;
    };

    int ya = reflect_i(y0 - 4, IMH) * IMW;
    float rA = p0[ya + rx], gA = p1[ya + rx], cA = p2[ya + rx];
    int yb = reflect_i(y0 - 3, IMH) * IMW;
    float rB = p0[yb + rx], gB = p1[yb + rx], cB = p2[yb + rx];

    #pragma unroll 2
    for (int tt = 0; tt < (RB + 8) / 2; ++tt) {
        int yL = y0 - 4 + 2 * tt;
        float grayA = 0.1495f * rA + 0.2935f * gA + 0.057f * cA + 0.5f;
        int yr = reflect_i(yL + 2, IMH) * IMW;
        rA = p0[yr + rx]; gA = p1[yr + rx]; cA = p2[yr + rx];
        process(yL, grayA);
        float grayB = 0.1495f * rB + 0.2935f * gB + 0.057f * cB + 0.5f;
        int yr2 = reflect_i(yL + 3, IMH) * IMW;
        rB = p0[yr2 + rx]; gB = p1[yr2 + rx]; cB = p2[yr2 + rx];
        process(yL + 1, grayB);
    }
}

__global__ __launch_bounds__(256)
void canny_stream(const float* __restrict__ data, float* __restrict__ out) {
    const int lane = threadIdx.x & 63;
    const int wid  = (blockIdx.x << 2) + (threadIdx.x >> 6);
    const int wc   = wid % NWC;
    const int t2   = wid / NWC;
    const int band = t2 & (NBAND - 1);
    const int bat  = t2 >> 5;            // t2 / NBAND

    const int c0 = OUTW * wc - 4;
    const int cx = c0 + lane;
    const int y0 = band * RB;

    const size_t plane = (size_t)(IMH * IMW);
    const float* p0 = data + (size_t)bat * 3 * plane;
    const float* p1 = p0 + plane;
    const float* p2 = p1 + plane;
    float* outp = out + (size_t)bat * plane;

    const int rx  = reflect_i(cx, IMW);
    const int ixm = (cx - 1 < 0 ? 0 : (cx - 1 >= IMW ? IMW - 1 : cx - 1)) - c0;
    const int ixp = (cx + 1 < 0 ? 0 : (cx + 1 >= IMW ? IMW - 1 : cx + 1)) - c0;

    #pragma unroll 1
    for (int rep = 0; rep < REPEATS; ++rep) {
        if (band == 0 || band == NBAND - 1)
            run_band<true>(p0, p1, p2, outp, y0, rx, cx, ixm, ixp, lane);
        else
            run_band<false>(p0, p1, p2, outp, y0, rx, cx, ixm, ixp, lane);
    }
}

extern "C" void kernel_launch(void* const* d_in, const int* in_sizes, int n_in,
                              void* d_out, int out_size, void* d_ws, size_t ws_size,
                              hipStream_t stream) {
    const float* data = (const float*)d_in[0];
    float* out = (float*)d_out;
    int B = in_sizes[0] / (3 * IMH * IMW);   // 16
    int blocks = (B * NBAND * NWC) / 4;      // 4 waves per 256-thread block
    canny_stream<<<blocks, dim3(256, 1, 1), 0, stream>>>(data, out);
}

// Round 9
// 98.026 us; speedup vs baseline: 1.0923x; 1.0923x over previous
//
#include <hip/hip_runtime.h>
#include <math.h>

#define IMH 512
#define IMW 512
#define RB    16    // output rows per wave-band
#define NBAND 32    // IMH / RB
#define NWC   5     // wave-columns: 2 px/lane -> 128-col coverage, 120 out cols
#define OUTW  120

__device__ __forceinline__ int reflect_i(int v, int n) {
    if (v < 0) v = -v;
    if (v >= n) v = 2 * n - 2 - v;
    return v;
}
// DPP wave shifts (VALU pipe). 0x138=wave_shr1 (lane i <- i-1), 0x130=wave_shl1
// (lane i <- i+1) — direction anchored by R4(shfl)==R6(dpp) bit-identical results.
__device__ __forceinline__ float dpp_shr1(float x) {
    int i = __float_as_int(x);
    return __int_as_float(__builtin_amdgcn_update_dpp(i, i, 0x138, 0xF, 0xF, false));
}
__device__ __forceinline__ float dpp_shl1(float x) {
    int i = __float_as_int(x);
    return __int_as_float(__builtin_amdgcn_update_dpp(i, i, 0x130, 0xF, 0xF, false));
}

// One wave streams a 128-col x RB-row band; lane holds cols (cx0, cx0+1).
// YB: band touches top/bottom rows. XB: wave touches left/right cols.
template <bool YB, bool XB>
__device__ __forceinline__ void run_band(const float* __restrict__ p0,
                                         const float* __restrict__ p1,
                                         const float* __restrict__ p2,
                                         float* __restrict__ outp,
                                         int y0, int c0, int lane) {
    const float w0 = 0.05448868f, w1 = 0.24420134f, w2 = 0.40261995f;
    const int cx0 = c0 + 2 * lane, cx1 = cx0 + 1;
    int rx0 = 0, rx1 = 0;
    bool vx0 = true, vx1 = true;
    if (XB) {
        rx0 = reflect_i(cx0, IMW); rx1 = reflect_i(cx1, IMW);
        vx0 = (unsigned)cx0 < (unsigned)IMW;
        vx1 = (unsigned)cx1 < (unsigned)IMW;
    }
    const bool storeok = (lane >= 2) && (lane <= 61) &&
                         (!XB || (unsigned)cx0 < (unsigned)IMW);

    // rings: h (rows yL-4..yL-1) per component; b/l/r and m/l/r depth-2; grad pairs
    float hA0 = 0, hA1 = 0, hA2 = 0, hA3 = 0, hB0 = 0, hB1 = 0, hB2 = 0, hB3 = 0;
    float bp0_1 = 0, bp1_1 = 0, bp0_0 = 0, bp1_0 = 0;
    float bl_1 = 0, bl_0 = 0, br_1 = 0, br_0 = 0;
    float mp0_1 = 0, mp1_1 = 0, mp0_0 = 0, mp1_0 = 0;
    float ml_1 = 0, ml_0 = 0, mr_1 = 0, mr_0 = 0;
    float gxp0 = 0, gxp1 = 0, gyp0 = 0, gyp1 = 0;

    auto loadrow = [&](int y, float2& R, float2& G, float2& Bc) {
        int yy = YB ? reflect_i(y, IMH) : y;
        int yo = yy * IMW;
        if (XB) {
            R.x = p0[yo + rx0]; R.y = p0[yo + rx1];
            G.x = p1[yo + rx0]; G.y = p1[yo + rx1];
            Bc.x = p2[yo + rx0]; Bc.y = p2[yo + rx1];
        } else {
            R  = *(const float2*)(p0 + yo + cx0);
            G  = *(const float2*)(p1 + yo + cx0);
            Bc = *(const float2*)(p2 + yo + cx0);
        }
    };
    // gray without +0.5: constant offset cancels exactly in the Sobel differences
    auto grayf = [&](const float2& R, const float2& G, const float2& Bc) {
        float2 g;
        g.x = 0.1495f * R.x + 0.2935f * G.x + 0.057f * Bc.x;
        g.y = 0.1495f * R.y + 0.2935f * G.y + 0.057f * Bc.y;
        return g;
    };

    auto process = [&](int yL, float2 Gp) {
        // horizontal blur: pair + neighbor pairs via 4 DPP
        float g1L = dpp_shr1(Gp.y);   // col 2L-1
        float g0L = dpp_shr1(Gp.x);   // col 2L-2
        float g0R = dpp_shl1(Gp.x);   // col 2L+2
        float g1R = dpp_shl1(Gp.y);   // col 2L+3
        float h0n = w0 * (g0L + g0R) + w1 * (g1L + Gp.y) + w2 * Gp.x;
        float h1n = w0 * (g1L + g1R) + w1 * (Gp.x + g0R) + w2 * Gp.y;
        // vertical blur -> row v = yL-2
        float b0n = w0 * (hA0 + h0n) + w1 * (hA1 + hA3) + w2 * hA2;
        float b1n = w0 * (hB0 + h1n) + w1 * (hB1 + hB3) + w2 * hB2;
        float bl1n = dpp_shr1(b1n);   // blurred col 2L-1
        float br0n = dpp_shl1(b0n);   // blurred col 2L+2
        if (XB) {                      // edge-clamp at image x-borders
            if (cx0 == 0)       bl1n = b0n;
            if (cx1 == IMW - 1) br0n = b1n;
        }
        // sobel -> row u = yL-3 (rows edge-clamped at y-borders)
        int u = yL - 3;
        float t_b0 = bp0_1, t_b1 = bp1_1, t_bl = bl_1, t_br = br_1;   // row u-1
        float n_b0 = b0n,   n_b1 = b1n,   n_bl = bl1n, n_br = br0n;   // row u+1
        if (YB) {
            if (u == 0)       { t_b0 = bp0_0; t_b1 = bp1_0; t_bl = bl_0; t_br = br_0; }
            if (u == IMH - 1) { n_b0 = bp0_0; n_b1 = bp1_0; n_bl = bl_0; n_br = br_0; }
        }
        float gx0 = (t_b1 - t_bl) + 2.0f * (bp1_0 - bl_0) + (n_b1 - n_bl);
        float gy0 = (n_bl - t_bl) + 2.0f * (n_b0 - t_b0) + (n_b1 - t_b1);
        float gx1 = (t_br - t_b0) + 2.0f * (br_0 - bp0_0) + (n_br - n_b0);
        float gy1 = (n_b0 - t_b0) + 2.0f * (n_b1 - t_b1) + (n_br - t_br);
        float mg0 = __builtin_amdgcn_sqrtf(gx0 * gx0 + gy0 * gy0 + 1e-6f);
        float mg1 = __builtin_amdgcn_sqrtf(gx1 * gx1 + gy1 * gy1 + 1e-6f);
        if (XB) { if (!vx0) mg0 = 0.0f; if (!vx1) mg1 = 0.0f; }  // NMS zero-pad cols
        float mln = dpp_shr1(mg1);    // mag col 2L-1
        float mrn = dpp_shl1(mg0);    // mag col 2L+2
        // NMS -> row s = yL-4 (uniform guard)
        int s = yL - 4;
        if (s >= y0) {
            float pm0 = mp0_1, pm1 = mp1_1, pml = ml_1, pmr = mr_1;   // row s-1
            float nm0 = mg0,   nm1 = mg1,   nml = mln,  nmr = mrn;    // row s+1
            if (YB) {
                if (s == 0)       { pm0 = 0; pm1 = 0; pml = 0; pmr = 0; }
                if (s == IMH - 1) { nm0 = 0; nm1 = 0; nml = 0; nmr = 0; }
            }
            // px0 (col 2L)
            float ax0 = fabsf(gxp0), ay0 = fabsf(gyp0);
            bool ew0 = ay0 <= 0.41421356237f * ax0;
            bool ns0 = ay0 >= 2.41421356237f * ax0;
            bool d10 = gxp0 * gyp0 > 0.0f;          // (dy=-1,dx=+1) axis
            float n1a = ew0 ? mp1_0 : (ns0 ? nm0 : (d10 ? pm1 : nm1));
            float n2a = ew0 ? ml_0  : (ns0 ? pm0 : (d10 ? nml : pml));
            float o0 = (mp0_0 > n1a && mp0_0 > n2a) ? mp0_0 : 0.0f;
            // px1 (col 2L+1)
            float ax1 = fabsf(gxp1), ay1 = fabsf(gyp1);
            bool ew1 = ay1 <= 0.41421356237f * ax1;
            bool ns1 = ay1 >= 2.41421356237f * ax1;
            bool d11 = gxp1 * gyp1 > 0.0f;
            float n1b = ew1 ? mr_0  : (ns1 ? nm1 : (d11 ? pmr : nmr));
            float n2b = ew1 ? mp0_0 : (ns1 ? pm1 : (d11 ? nm0 : pm0));
            float o1 = (mp1_0 > n1b && mp1_0 > n2b) ? mp1_0 : 0.0f;
            if (storeok) {
                union { float f[2]; unsigned long long u; } pk;
                pk.f[0] = o0; pk.f[1] = o1;
                __builtin_nontemporal_store(
                    pk.u, (unsigned long long*)(outp + (size_t)s * IMW + cx0));
            }
        }
        // rotate rings
        hA0 = hA1; hA1 = hA2; hA2 = hA3; hA3 = h0n;
        hB0 = hB1; hB1 = hB2; hB2 = hB3; hB3 = h1n;
        bp0_1 = bp0_0; bp0_0 = b0n;  bp1_1 = bp1_0; bp1_0 = b1n;
        bl_1 = bl_0; bl_0 = bl1n;    br_1 = br_0; br_0 = br0n;
        mp0_1 = mp0_0; mp0_0 = mg0;  mp1_1 = mp1_0; mp1_0 = mg1;
        ml_1 = ml_0; ml_0 = mln;     mr_1 = mr_0; mr_0 = mrn;
        gxp0 = gx0; gxp1 = gx1; gyp0 = gy0; gyp1 = gy1;
    };

    // depth-2 A/B prefetch, rows yL = y0-4 .. y0+RB+3
    float2 rA, gA, cA, rB, gB, cB;
    loadrow(y0 - 4, rA, gA, cA);
    loadrow(y0 - 3, rB, gB, cB);

    #pragma unroll 2
    for (int tt = 0; tt < (RB + 8) / 2; ++tt) {
        int yL = y0 - 4 + 2 * tt;
        float2 GA = grayf(rA, gA, cA);
        loadrow(yL + 2, rA, gA, cA);
        process(yL, GA);
        float2 GB = grayf(rB, gB, cB);
        loadrow(yL + 3, rB, gB, cB);
        process(yL + 1, GB);
    }
}

__global__ __launch_bounds__(256)
void canny_stream(const float* __restrict__ data, float* __restrict__ out) {
    const int lane = threadIdx.x & 63;
    const int wid  = (blockIdx.x << 2) + (threadIdx.x >> 6);
    const int wc   = wid % NWC;
    const int t2   = wid / NWC;
    const int band = t2 & (NBAND - 1);
    const int bat  = t2 >> 5;            // t2 / NBAND

    const int c0 = OUTW * wc - 4;
    const int y0 = band * RB;

    const size_t plane = (size_t)(IMH * IMW);
    const float* p0 = data + (size_t)bat * 3 * plane;
    const float* p1 = p0 + plane;
    const float* p2 = p1 + plane;
    float* outp = out + (size_t)bat * plane;

    const bool yb = (band == 0) || (band == NBAND - 1);
    const bool xb = (wc == 0) || (wc == NWC - 1);
    if (yb) {
        if (xb) run_band<true, true >(p0, p1, p2, outp, y0, c0, lane);
        else    run_band<true, false>(p0, p1, p2, outp, y0, c0, lane);
    } else {
        if (xb) run_band<false, true >(p0, p1, p2, outp, y0, c0, lane);
        else    run_band<false, false>(p0, p1, p2, outp, y0, c0, lane);
    }
}

extern "C" void kernel_launch(void* const* d_in, const int* in_sizes, int n_in,
                              void* d_out, int out_size, void* d_ws, size_t ws_size,
                              hipStream_t stream) {
    const float* data = (const float*)d_in[0];
    float* out = (float*)d_out;
    int B = in_sizes[0] / (3 * IMH * IMW);   // 16
    int blocks = (B * NBAND * NWC) / 4;      // 4 waves per 256-thread block = 640
    canny_stream<<<blocks, dim3(256, 1, 1), 0, stream>>>(data, out);
}

// Round 10
// 89.591 us; speedup vs baseline: 1.1952x; 1.0941x over previous
//
#include <hip/hip_runtime.h>
#include <math.h>

#define IMH 512
#define IMW 512
#define RB    16    // output rows per wave-band
#define NBAND 32    // IMH / RB
#define NWC   10    // wave-columns: out width 56 each, c0 = 56*wc - 4
#define OUTW  56

__device__ __forceinline__ int reflect_i(int v, int n) {
    if (v < 0) v = -v;
    if (v >= n) v = 2 * n - 2 - v;
    return v;
}
// DPP wave shifts (VALU pipe). 0x138=wave_shr1 (lane i <- i-1), 0x130=wave_shl1
// (lane i <- i+1) — direction anchored by R4(shfl)==R6(dpp) identical results.
__device__ __forceinline__ float dpp_shr1(float x) {
    int i = __float_as_int(x);
    return __int_as_float(__builtin_amdgcn_update_dpp(i, i, 0x138, 0xF, 0xF, false));
}
__device__ __forceinline__ float dpp_shl1(float x) {
    int i = __float_as_int(x);
    return __int_as_float(__builtin_amdgcn_update_dpp(i, i, 0x130, 0xF, 0xF, false));
}

// One wave streams a 64-col x RB-row band; lane = column cx = c0+lane.
// YB: band touches top/bottom image rows. XB: wave touches left/right cols.
// Fully unrolled: ring rotations become register renames; emit guard folds.
template <bool YB, bool XB>
__device__ __forceinline__ void run_band(const float* __restrict__ p0,
                                         const float* __restrict__ p1,
                                         const float* __restrict__ p2,
                                         float* __restrict__ outp,
                                         int y0, int c0, int lane) {
    const float w0 = 0.05448868f, w1 = 0.24420134f, w2 = 0.40261995f;
    const int cx = c0 + lane;
    const int rx = XB ? reflect_i(cx, IMW) : cx;   // col reflect only at x-borders
    int ixm = lane - 1, ixp = lane + 1;
    if (XB) {
        ixm = (cx - 1 < 0 ? 0 : (cx - 1 >= IMW ? IMW - 1 : cx - 1)) - c0;
        ixp = (cx + 1 < 0 ? 0 : (cx + 1 >= IMW ? IMW - 1 : cx + 1)) - c0;
    }
    const bool storeok = (lane >= 4) && (lane < 60) &&
                         (!XB || (unsigned)cx < (unsigned)IMW);

    // rolling rings (renamed away under full unroll)
    float h0 = 0, h1 = 0, h2 = 0, h3 = 0;
    float b_1 = 0, b_0 = 0, bl_1 = 0, bl_0 = 0, br_1 = 0, br_0 = 0;
    float m_1 = 0, m_0 = 0, ml_1 = 0, ml_0 = 0, mr_1 = 0, mr_0 = 0;
    float gxp = 0, gyp = 0;

    auto process = [&](int yL, float gray, bool emit) {
        float gm1 = dpp_shr1(gray);
        float gm2 = dpp_shr1(gm1);
        float gp1 = dpp_shl1(gray);
        float gp2 = dpp_shl1(gp1);
        float hnew = w0 * (gm2 + gp2) + w1 * (gm1 + gp1) + w2 * gray;
        float bnew = w0 * (h0 + hnew) + w1 * (h1 + h3) + w2 * h2;
        float blnew, brnew;     // edge-clamped col neighbors of blurred
        if (XB) { blnew = __shfl(bnew, ixm); brnew = __shfl(bnew, ixp); }
        else    { blnew = dpp_shr1(bnew);    brnew = dpp_shl1(bnew); }
        int u = yL - 3;
        float ta = b_1, tla = bl_1, tra = br_1;       // row u-1
        float tb = bnew, tlb = blnew, trb = brnew;    // row u+1
        if (YB) {
            if (u == 0)       { ta = b_0; tla = bl_0; tra = br_0; }
            if (u == IMH - 1) { tb = b_0; tlb = bl_0; trb = br_0; }
        }
        float gx = (tra - tla) + 2.0f * (br_0 - bl_0) + (trb - tlb);
        float gy = (tlb - tla) + 2.0f * (tb - ta) + (trb - tra);
        float mnew = __builtin_amdgcn_sqrtf(gx * gx + gy * gy + 1e-6f);
        if (XB) { if ((unsigned)cx >= (unsigned)IMW) mnew = 0.0f; }  // NMS zero-pad
        float mlnew = dpp_shr1(mnew);
        float mrnew = dpp_shl1(mnew);
        if (emit) {            // compile-time under full unroll
            int s = yL - 4;
            float pm = m_1, pml = ml_1, pmr = mr_1;
            float nm = mnew, nml = mlnew, nmr = mrnew;
            if (YB) {
                if (s == 0)       { pm = 0; pml = 0; pmr = 0; }
                if (s == IMH - 1) { nm = 0; nml = 0; nmr = 0; }
            }
            float ax = fabsf(gxp), ay = fabsf(gyp);
            bool ew = (ay <= 0.41421356237f * ax);
            bool ns = (ay >= 2.41421356237f * ax);
            bool d1 = (gxp * gyp > 0.0f);
            float n1 = ew ? mr_0 : (ns ? nm : (d1 ? pmr : nmr));
            float n2 = ew ? ml_0 : (ns ? pm : (d1 ? nml : pml));
            float mag = m_0;
            float o = (mag > n1 && mag > n2) ? mag : 0.0f;
            if (storeok)
                __builtin_nontemporal_store(o, &outp[(size_t)s * IMW + cx]);
        }
        h0 = h1; h1 = h2; h2 = h3; h3 = hnew;
        b_1 = b_0;  b_0 = bnew;
        bl_1 = bl_0; bl_0 = blnew;
        br_1 = br_0; br_0 = brnew;
        m_1 = m_0;  m_0 = mnew;
        ml_1 = ml_0; ml_0 = mlnew;
        mr_1 = mr_0; mr_0 = mrnew;
        gxp = gx; gyp = gy;
    };

    // depth-2 A/B prefetch, rows yL = y0-4 .. y0+RB+3
    int ya = (YB ? reflect_i(y0 - 4, IMH) : (y0 - 4)) * IMW;
    float rA = p0[ya + rx], gA = p1[ya + rx], cA = p2[ya + rx];
    int yb = (YB ? reflect_i(y0 - 3, IMH) : (y0 - 3)) * IMW;
    float rB = p0[yb + rx], gB = p1[yb + rx], cB = p2[yb + rx];

    #pragma unroll
    for (int tt = 0; tt < (RB + 8) / 2; ++tt) {
        int yL = y0 - 4 + 2 * tt;
        float grayA = 0.1495f * rA + 0.2935f * gA + 0.057f * cA;
        if (tt < (RB + 8) / 2 - 1) {
            int yr = (YB ? reflect_i(yL + 2, IMH) : (yL + 2)) * IMW;
            rA = p0[yr + rx]; gA = p1[yr + rx]; cA = p2[yr + rx];
        }
        process(yL, grayA, tt >= 4);
        float grayB = 0.1495f * rB + 0.2935f * gB + 0.057f * cB;
        if (tt < (RB + 8) / 2 - 1) {
            int yr2 = (YB ? reflect_i(yL + 3, IMH) : (yL + 3)) * IMW;
            rB = p0[yr2 + rx]; gB = p1[yr2 + rx]; cB = p2[yr2 + rx];
        }
        process(yL + 1, grayB, tt >= 4);
    }
}

__global__ __launch_bounds__(256)
void canny_stream(const float* __restrict__ data, float* __restrict__ out) {
    const int lane = threadIdx.x & 63;
    const int wid  = (blockIdx.x << 2) + (threadIdx.x >> 6);
    const int wc   = wid % NWC;
    const int t2   = wid / NWC;
    const int band = t2 & (NBAND - 1);
    const int bat  = t2 >> 5;            // t2 / NBAND

    const int c0 = OUTW * wc - 4;
    const int y0 = band * RB;

    const size_t plane = (size_t)(IMH * IMW);
    const float* p0 = data + (size_t)bat * 3 * plane;
    const float* p1 = p0 + plane;
    const float* p2 = p1 + plane;
    float* outp = out + (size_t)bat * plane;

    const bool yb = (band == 0) || (band == NBAND - 1);
    const bool xb = (wc == 0) || (wc == NWC - 1);
    if (yb) {
        if (xb) run_band<true, true >(p0, p1, p2, outp, y0, c0, lane);
        else    run_band<true, false>(p0, p1, p2, outp, y0, c0, lane);
    } else {
        if (xb) run_band<false, true >(p0, p1, p2, outp, y0, c0, lane);
        else    run_band<false, false>(p0, p1, p2, outp, y0, c0, lane);
    }
}

extern "C" void kernel_launch(void* const* d_in, const int* in_sizes, int n_in,
                              void* d_out, int out_size, void* d_ws, size_t ws_size,
                              hipStream_t stream) {
    const float* data = (const float*)d_in[0];
    float* out = (float*)d_out;
    int B = in_sizes[0] / (3 * IMH * IMW);   // 16
    int blocks = (B * NBAND * NWC) / 4;      // 4 waves/block = 1280 blocks, 5120 waves
    canny_stream<<<blocks, dim3(256, 1, 1), 0, stream>>>(data, out);
}